// Round 11
// baseline (203.203 us; speedup 1.0000x reference)
//
#include <hip/hip_runtime.h>
#include <stdint.h>

#define B_N 1024
#define K_N 64
#define O_N 4096
#define I_N 4096

typedef float nvec4 __attribute__((ext_vector_type(4)));

// ---------------------------------------------------------------------------
// Transpose x (B x K) -> xT (K x B) and idx likewise (bit-copy via float).
// ---------------------------------------------------------------------------
__global__ __launch_bounds__(256) void xpose_small(
    const float* __restrict__ x, const float* __restrict__ idxf,
    float* __restrict__ xT, float* __restrict__ idxTf) {
  __shared__ float tile[64][65];
  const int t = threadIdx.x;
  const int which = blockIdx.x >> 4;
  const int b0 = (blockIdx.x & 15) * 64;
  const float* src = which ? idxf : x;
  float* dst = which ? idxTf : xT;
  {
    const int r = t & 63;
    const int q0 = t >> 6;
#pragma unroll
    for (int jj = 0; jj < 4; ++jj) {
      const int q = q0 + 4 * jj;
      const float4 v = *(const float4*)(src + (size_t)(b0 + r) * K_N + 4 * q);
      tile[r][4 * q + 0] = v.x;
      tile[r][4 * q + 1] = v.y;
      tile[r][4 * q + 2] = v.z;
      tile[r][4 * q + 3] = v.w;
    }
  }
  __syncthreads();
  {
    const int kk = t & 63;
    const int q0 = t >> 6;
#pragma unroll
    for (int jj = 0; jj < 4; ++jj) {
      const int qb = q0 + 4 * jj;
      float4 v;
      v.x = tile[4 * qb + 0][kk];
      v.y = tile[4 * qb + 1][kk];
      v.z = tile[4 * qb + 2][kk];
      v.w = tile[4 * qb + 3][kk];
      *(float4*)(dst + (size_t)kk * B_N + b0 + 4 * qb) = v;
    }
  }
}

// ---------------------------------------------------------------------------
// Gathered matvec, W rows LDS-resident. R10 reshape: 2 o-rows / 32 KB tile /
// 512 threads / 2 b per thread -> 4 blocks/CU x 8 waves = 32 waves/CU (100%
// occupancy; R9 measured only 50%), 2048 blocks = 8 exact dispatch rounds,
// and b64 gathers (2 banks/lane vs 4) to cut random-gather conflict cost.
// Bit-exact: per (b,o) ascending-k chain, unfused mul/add, bias last.
// ---------------------------------------------------------------------------
__global__ __launch_bounds__(512, 8) void gemv_lds(
    const float* __restrict__ W, const float* __restrict__ xT,
    const int* __restrict__ idxT, const float* __restrict__ bias,
    float* __restrict__ res) {
  __shared__ float2 Wi[I_N];  // 32 KB: Wi[i] = {W[o0][i], W[o0+1][i]}
  const int t = threadIdx.x;  // 0..511
  const int o0 = blockIdx.x * 2;

  // stage 2 rows; thread covers i-range [8t, 8t+8); b128 LDS writes
  {
    const int i0 = 8 * t;
    const nvec4 a0 = __builtin_nontemporal_load(
        (const nvec4*)(W + (size_t)(o0 + 0) * I_N + i0));
    const nvec4 a1 = __builtin_nontemporal_load(
        (const nvec4*)(W + (size_t)(o0 + 0) * I_N + i0 + 4));
    const nvec4 b0 = __builtin_nontemporal_load(
        (const nvec4*)(W + (size_t)(o0 + 1) * I_N + i0));
    const nvec4 b1 = __builtin_nontemporal_load(
        (const nvec4*)(W + (size_t)(o0 + 1) * I_N + i0 + 4));
    *(float4*)&Wi[i0 + 0] = make_float4(a0.x, b0.x, a0.y, b0.y);
    *(float4*)&Wi[i0 + 2] = make_float4(a0.z, b0.z, a0.w, b0.w);
    *(float4*)&Wi[i0 + 4] = make_float4(a1.x, b1.x, a1.y, b1.y);
    *(float4*)&Wi[i0 + 6] = make_float4(a1.z, b1.z, a1.w, b1.w);
  }
  __syncthreads();

  const float2 bv = *(const float2*)(bias + o0);
#pragma unroll
  for (int c = 0; c < 2; ++c) {
    const int b = c * 512 + t;
    float2 a = make_float2(0.f, 0.f);
    float xr[4];
    int ir[4];
#pragma unroll
    for (int d = 0; d < 4; ++d) {
      xr[d] = xT[d * B_N + b];
      ir[d] = idxT[d * B_N + b];
    }
#pragma unroll
    for (int k = 0; k < K_N; ++k) {
      const float xk = xr[k & 3];
      const int i = ir[k & 3];
      if (k + 4 < K_N) {
        xr[k & 3] = xT[(k + 4) * B_N + b];
        ir[k & 3] = idxT[(k + 4) * B_N + b];
      }
      const float2 w = Wi[i];  // ds_read_b64 gather
      a.x = __fadd_rn(a.x, __fmul_rn(xk, w.x));
      a.y = __fadd_rn(a.y, __fmul_rn(xk, w.y));
    }
    a.x = __fadd_rn(a.x, bv.x);
    a.y = __fadd_rn(a.y, bv.y);
    *(float2*)(res + (size_t)b * O_N + o0) = a;
  }
}

// ---------------------------------------------------------------------------
// Exact top-64 per row (UNCHANGED from R10 for clean attribution).
// ---------------------------------------------------------------------------
__global__ __launch_bounds__(256) void topk_phase(
    const float* __restrict__ res, float* __restrict__ out) {
  __shared__ __align__(16) unsigned int hist[256];
  __shared__ unsigned int hist4[4 * 257];
  __shared__ unsigned int sel_u[64];
  __shared__ int sel_i[64];
  __shared__ int eqlist[128];
  __shared__ unsigned int s_cntgt, s_cnteq;
  __shared__ unsigned int s_remaining, s_prefix;

  const int t = threadIdx.x;
  const int b = blockIdx.x;
  const int w = t >> 6;

  hist[t] = 0u;
#pragma unroll
  for (int j = 0; j < 5; ++j) {
    const int z = t + 256 * j;
    if (z < 4 * 257) hist4[z] = 0u;
  }
  if (t == 0) {
    s_remaining = 64u;
    s_prefix = 0u;
    s_cntgt = 0u;
    s_cnteq = 0u;
  }

  unsigned int myu[16];
#pragma unroll
  for (int jf = 0; jf < 4; ++jf) {
    const float4 v =
        *(const float4*)(res + (size_t)b * O_N + 1024 * jf + 4 * t);
    const float fv[4] = {v.x, v.y, v.z, v.w};
#pragma unroll
    for (int c = 0; c < 4; ++c) {
      const unsigned int s = __float_as_uint(fv[c]);
      myu[jf * 4 + c] = (s & 0x80000000u) ? ~s : (s | 0x80000000u);
    }
  }
  __syncthreads();

  for (int round = 3; round >= 0; --round) {
    const int shift = round * 8;
    const unsigned int pfx = s_prefix;
    const unsigned int rem = s_remaining;
    if (round == 3) {
#pragma unroll
      for (int j = 0; j < 16; ++j)
        atomicAdd(&hist4[w * 257 + (myu[j] >> 24)], 1u);
    } else {
      const unsigned int himask = 0xFFFFFFFFu << (shift + 8);
#pragma unroll
      for (int j = 0; j < 16; ++j) {
        if ((myu[j] & himask) == (pfx & himask))
          atomicAdd(&hist[(myu[j] >> shift) & 255u], 1u);
      }
    }
    __syncthreads();
    if (t < 64) {
      uint4 h;
      if (round == 3) {
        h.x = hist4[0 * 257 + 4 * t + 0] + hist4[1 * 257 + 4 * t + 0] +
              hist4[2 * 257 + 4 * t + 0] + hist4[3 * 257 + 4 * t + 0];
        h.y = hist4[0 * 257 + 4 * t + 1] + hist4[1 * 257 + 4 * t + 1] +
              hist4[2 * 257 + 4 * t + 1] + hist4[3 * 257 + 4 * t + 1];
        h.z = hist4[0 * 257 + 4 * t + 2] + hist4[1 * 257 + 4 * t + 2] +
              hist4[2 * 257 + 4 * t + 2] + hist4[3 * 257 + 4 * t + 2];
        h.w = hist4[0 * 257 + 4 * t + 3] + hist4[1 * 257 + 4 * t + 3] +
              hist4[2 * 257 + 4 * t + 3] + hist4[3 * 257 + 4 * t + 3];
      } else {
        h = *(const uint4*)&hist[4 * t];
      }
      unsigned int s0 = h.x + h.y + h.z + h.w;
      unsigned int run = s0;
#pragma unroll
      for (int off = 1; off < 64; off <<= 1) {
        const unsigned int v = __shfl_down(run, off, 64);
        if (t + off < 64) run += v;
      }
      const unsigned int above = run - s0;
      unsigned int cge[4], cgt[4];
      cgt[3] = above;
      cge[3] = above + h.w;
      cgt[2] = cge[3];
      cge[2] = cge[3] + h.z;
      cgt[1] = cge[2];
      cge[1] = cge[2] + h.y;
      cgt[0] = cge[1];
      cge[0] = cge[1] + h.x;
#pragma unroll
      for (int j = 0; j < 4; ++j) {
        if (cge[j] >= rem && cgt[j] < rem) {
          s_prefix = pfx | ((unsigned int)(4 * t + j) << shift);
          s_remaining = rem - cgt[j];
        }
      }
      *(uint4*)&hist[4 * t] = make_uint4(0u, 0u, 0u, 0u);
    }
    __syncthreads();
  }
  const unsigned int ustar = s_prefix;

#pragma unroll
  for (int j = 0; j < 16; ++j) {
    const unsigned int u = myu[j];
    const int oi = 4 * t + (j & 3) + 1024 * (j >> 2);
    if (u > ustar) {
      unsigned int p = atomicAdd(&s_cntgt, 1u);
      sel_u[p] = u;
      sel_i[p] = oi;
    } else if (u == ustar) {
      unsigned int p = atomicAdd(&s_cnteq, 1u);
      if (p < 128u) eqlist[p] = oi;
    }
  }
  __syncthreads();

  if (t == 0 && s_cnteq > 1u) {
    int n = (int)(s_cnteq < 128u ? s_cnteq : 128u);
    for (int a = 1; a < n; ++a) {
      int v = eqlist[a];
      int c = a;
      while (c > 0 && eqlist[c - 1] > v) {
        eqlist[c] = eqlist[c - 1];
        --c;
      }
      eqlist[c] = v;
    }
  }
  __syncthreads();

  if (t < 64) {
    const int n_gt = (int)s_cntgt;
    unsigned int u;
    int oi;
    if (t < n_gt) {
      u = sel_u[t];
      oi = sel_i[t];
    } else {
      u = ustar;
      oi = eqlist[t - n_gt];
    }
    unsigned long long key =
        ((unsigned long long)(~u) << 32) | (unsigned int)oi;
    for (int kk = 2; kk <= 64; kk <<= 1) {
      for (int jj = kk >> 1; jj > 0; jj >>= 1) {
        unsigned long long partner = __shfl_xor(key, jj, 64);
        const bool up = ((t & kk) == 0);
        const bool lower = ((t & jj) == 0);
        unsigned long long mn = key < partner ? key : partner;
        unsigned long long mx = key < partner ? partner : key;
        key = (up == lower) ? mn : mx;
      }
    }
    const unsigned int su = ~(unsigned int)(key >> 32);
    const int so = (int)(key & 0xFFFFFFFFu);
    const float f = (su & 0x80000000u) ? __uint_as_float(su ^ 0x80000000u)
                                       : __uint_as_float(~su);
    out[b * 64 + t] = f;
    out[B_N * 64 + b * 64 + t] = (float)so;
  }
}

// ---------------------------------------------------------------------------
// Fallback: fused single-kernel path on raw W (used only if ws is too small).
// ---------------------------------------------------------------------------
__global__ __launch_bounds__(256) void selgemv_topk(
    const float* __restrict__ x, const float* __restrict__ Wsrc,
    const float* __restrict__ bias, const int* __restrict__ idx,
    float* __restrict__ out) {
  __shared__ float sx[K_N];
  __shared__ int si[K_N];
  __shared__ float svals[O_N];
  __shared__ unsigned int hist[256];
  __shared__ unsigned int scan[256];
  __shared__ unsigned int sel_u[64];
  __shared__ int sel_i[64];
  __shared__ int eqlist[128];
  __shared__ unsigned int s_T, s_ngt, s_cntgt, s_cnteq;
  __shared__ unsigned int s_remaining, s_prefix;

  const int t = threadIdx.x;
  const int b = blockIdx.x;

  if (t < K_N) {
    sx[t] = x[b * K_N + t];
    si[t] = idx[b * K_N + t];
  }
  if (t == 0) {
    s_remaining = 64u;
    s_prefix = 0u;
    s_cntgt = 0u;
    s_cnteq = 0u;
  }
  __syncthreads();

  float acc[16];
#pragma unroll
  for (int j = 0; j < 16; ++j) acc[j] = 0.0f;

  for (int k = 0; k < K_N; ++k) {
    const float xk = sx[k];
    const int ik = si[k];
#pragma unroll
    for (int j = 0; j < 4; ++j) {
      int o0 = (j * 256 + t) * 4;
#pragma unroll
      for (int c = 0; c < 4; ++c) {
        float w = Wsrc[(size_t)(o0 + c) * I_N + ik];
        acc[4 * j + c] = __fadd_rn(acc[4 * j + c], __fmul_rn(xk, w));
      }
    }
  }

#pragma unroll
  for (int j = 0; j < 4; ++j) {
    int g = j * 256 + t;
    float4 bb = ((const float4*)bias)[g];
    float4 r;
    r.x = __fadd_rn(acc[4 * j + 0], bb.x);
    r.y = __fadd_rn(acc[4 * j + 1], bb.y);
    r.z = __fadd_rn(acc[4 * j + 2], bb.z);
    r.w = __fadd_rn(acc[4 * j + 3], bb.w);
    ((float4*)svals)[g] = r;
  }
  __syncthreads();

  unsigned int myu[16];
#pragma unroll
  for (int j = 0; j < 16; ++j) {
    float f = svals[t + 256 * j];
    unsigned int s = __float_as_uint(f);
    myu[j] = (s & 0x80000000u) ? ~s : (s | 0x80000000u);
  }

  for (int round = 3; round >= 0; --round) {
    const int shift = round * 8;
    hist[t] = 0u;
    __syncthreads();
    const unsigned int pfx = s_prefix;
    const unsigned int rem = s_remaining;
    const unsigned int himask =
        (round == 3) ? 0u : (0xFFFFFFFFu << (shift + 8));
#pragma unroll
    for (int j = 0; j < 16; ++j) {
      if ((myu[j] & himask) == (pfx & himask))
        atomicAdd(&hist[(myu[j] >> shift) & 255u], 1u);
    }
    __syncthreads();
    scan[t] = hist[t];
    __syncthreads();
    for (int off = 1; off < 256; off <<= 1) {
      unsigned int v = (t + off < 256) ? scan[t + off] : 0u;
      __syncthreads();
      scan[t] += v;
      __syncthreads();
    }
    const unsigned int c_ge = scan[t];
    const unsigned int c_gt = (t < 255) ? scan[t + 1] : 0u;
    if (c_ge >= rem && c_gt < rem) {
      s_T = (unsigned int)t;
      s_ngt = c_gt;
    }
    __syncthreads();
    if (t == 0) {
      s_prefix |= (s_T << shift);
      s_remaining -= s_ngt;
    }
    __syncthreads();
  }
  const unsigned int ustar = s_prefix;

#pragma unroll
  for (int j = 0; j < 16; ++j) {
    const unsigned int u = myu[j];
    if (u > ustar) {
      unsigned int p = atomicAdd(&s_cntgt, 1u);
      sel_u[p] = u;
      sel_i[p] = t + 256 * j;
    } else if (u == ustar) {
      unsigned int p = atomicAdd(&s_cnteq, 1u);
      if (p < 128u) eqlist[p] = t + 256 * j;
    }
  }
  __syncthreads();

  if (t == 0 && s_cnteq > 1u) {
    int n = (int)(s_cnteq < 128u ? s_cnteq : 128u);
    for (int a = 1; a < n; ++a) {
      int v = eqlist[a];
      int c = a;
      while (c > 0 && eqlist[c - 1] > v) {
        eqlist[c] = eqlist[c - 1];
        --c;
      }
      eqlist[c] = v;
    }
  }
  __syncthreads();

  if (t < 64) {
    const int n_gt = (int)s_cntgt;
    unsigned int u;
    int oi;
    if (t < n_gt) {
      u = sel_u[t];
      oi = sel_i[t];
    } else {
      u = ustar;
      oi = eqlist[t - n_gt];
    }
    unsigned long long key =
        ((unsigned long long)(~u) << 32) | (unsigned int)oi;
    for (int kk = 2; kk <= 64; kk <<= 1) {
      for (int jj = kk >> 1; jj > 0; jj >>= 1) {
        unsigned long long partner = __shfl_xor(key, jj, 64);
        const bool up = ((t & kk) == 0);
        const bool lower = ((t & jj) == 0);
        unsigned long long mn = key < partner ? key : partner;
        unsigned long long mx = key < partner ? partner : key;
        key = (up == lower) ? mn : mx;
      }
    }
    const unsigned int su = ~(unsigned int)(key >> 32);
    const int so = (int)(key & 0xFFFFFFFFu);
    const float f = (su & 0x80000000u) ? __uint_as_float(su ^ 0x80000000u)
                                       : __uint_as_float(~su);
    out[b * 64 + t] = f;
    out[B_N * 64 + b * 64 + t] = (float)so;
  }
}

extern "C" void kernel_launch(void* const* d_in, const int* in_sizes, int n_in,
                              void* d_out, int out_size, void* d_ws,
                              size_t ws_size, hipStream_t stream) {
  const float* x = (const float*)d_in[0];     // (1024, 64)
  const float* W = (const float*)d_in[1];     // (4096, 4096)
  const float* bias = (const float*)d_in[2];  // (4096,)
  const int* idx = (const int*)d_in[3];       // (1024, 64) int32
  float* out = (float*)d_out;

  const size_t xT_bytes = (size_t)K_N * B_N * sizeof(float);   // 256 KB
  const size_t idxT_bytes = xT_bytes;                          // 256 KB
  const size_t res_bytes = (size_t)B_N * O_N * sizeof(float);  // 16 MB

  if (ws_size >= xT_bytes + idxT_bytes + res_bytes) {
    float* xT = (float*)d_ws;
    float* idxTf = (float*)((char*)d_ws + xT_bytes);
    float* res = (float*)((char*)d_ws + xT_bytes + idxT_bytes);
    xpose_small<<<32, 256, 0, stream>>>(x, (const float*)idx, xT, idxTf);
    gemv_lds<<<O_N / 2, 512, 0, stream>>>(W, xT, (const int*)idxTf, bias,
                                          res);
    topk_phase<<<B_N, 256, 0, stream>>>(res, out);
  } else {
    selgemv_topk<<<B_N, 256, 0, stream>>>(x, W, bias, idx, out);
  }
}

// Round 12
// 156.447 us; speedup vs baseline: 1.2989x; 1.2989x over previous
//
#include <hip/hip_runtime.h>
#include <stdint.h>

#define B_N 1024
#define K_N 64
#define O_N 4096
#define I_N 4096

typedef float nvec4 __attribute__((ext_vector_type(4)));

// ---------------------------------------------------------------------------
// Transpose x (B x K) -> xT (K x B) and idx likewise (bit-copy via float).
// ---------------------------------------------------------------------------
__global__ __launch_bounds__(256) void xpose_small(
    const float* __restrict__ x, const float* __restrict__ idxf,
    float* __restrict__ xT, float* __restrict__ idxTf) {
  __shared__ float tile[64][65];
  const int t = threadIdx.x;
  const int which = blockIdx.x >> 4;
  const int b0 = (blockIdx.x & 15) * 64;
  const float* src = which ? idxf : x;
  float* dst = which ? idxTf : xT;
  {
    const int r = t & 63;
    const int q0 = t >> 6;
#pragma unroll
    for (int jj = 0; jj < 4; ++jj) {
      const int q = q0 + 4 * jj;
      const float4 v = *(const float4*)(src + (size_t)(b0 + r) * K_N + 4 * q);
      tile[r][4 * q + 0] = v.x;
      tile[r][4 * q + 1] = v.y;
      tile[r][4 * q + 2] = v.z;
      tile[r][4 * q + 3] = v.w;
    }
  }
  __syncthreads();
  {
    const int kk = t & 63;
    const int q0 = t >> 6;
#pragma unroll
    for (int jj = 0; jj < 4; ++jj) {
      const int qb = q0 + 4 * jj;
      float4 v;
      v.x = tile[4 * qb + 0][kk];
      v.y = tile[4 * qb + 1][kk];
      v.z = tile[4 * qb + 2][kk];
      v.w = tile[4 * qb + 3][kk];
      *(float4*)(dst + (size_t)kk * B_N + b0 + 4 * qb) = v;
    }
  }
}

// ---------------------------------------------------------------------------
// Gathered matvec, W rows LDS-resident. EXACT R9 WINNER (measured 53-54 us).
// R10 (b64, 2-row tile) regressed: conflicts UP (inst count doubled, bank
// variance worse) and float2 epilogue caused 5.8x write amplification.
// R9 floor ledger: 13.7us b128 issue + 16.6us conflicts + 10us staging.
// 4 o-rows / 64KB interleaved tile / 1024 thr / 1 b per thread / b128.
// Bit-exact: per (b,o) ascending-k chain, unfused mul/add, bias last.
// ---------------------------------------------------------------------------
__global__ __launch_bounds__(1024, 4) void gemv_lds(
    const float* __restrict__ W, const float* __restrict__ xT,
    const int* __restrict__ idxT, const float* __restrict__ bias,
    float* __restrict__ res) {
  __shared__ float4 Wi[I_N];  // 64 KB
  const int t = threadIdx.x;
  const int o0 = blockIdx.x * 4;

  {
    const int i0 = 4 * t;
    const nvec4 r0 = __builtin_nontemporal_load(
        (const nvec4*)(W + (size_t)(o0 + 0) * I_N + i0));
    const nvec4 r1 = __builtin_nontemporal_load(
        (const nvec4*)(W + (size_t)(o0 + 1) * I_N + i0));
    const nvec4 r2 = __builtin_nontemporal_load(
        (const nvec4*)(W + (size_t)(o0 + 2) * I_N + i0));
    const nvec4 r3 = __builtin_nontemporal_load(
        (const nvec4*)(W + (size_t)(o0 + 3) * I_N + i0));
    Wi[i0 + 0] = make_float4(r0.x, r1.x, r2.x, r3.x);
    Wi[i0 + 1] = make_float4(r0.y, r1.y, r2.y, r3.y);
    Wi[i0 + 2] = make_float4(r0.z, r1.z, r2.z, r3.z);
    Wi[i0 + 3] = make_float4(r0.w, r1.w, r2.w, r3.w);
  }
  __syncthreads();

  const int b = t;
  const float4 bv = *(const float4*)(bias + o0);
  float4 a = make_float4(0.f, 0.f, 0.f, 0.f);
  float xr[4];
  int ir[4];
#pragma unroll
  for (int d = 0; d < 4; ++d) {
    xr[d] = xT[d * B_N + b];
    ir[d] = idxT[d * B_N + b];
  }
#pragma unroll
  for (int k = 0; k < K_N; ++k) {
    const float xk = xr[k & 3];
    const int i = ir[k & 3];
    if (k + 4 < K_N) {
      xr[k & 3] = xT[(k + 4) * B_N + b];
      ir[k & 3] = idxT[(k + 4) * B_N + b];
    }
    const float4 w = Wi[i];  // ds_read_b128 gather
    a.x = __fadd_rn(a.x, __fmul_rn(xk, w.x));
    a.y = __fadd_rn(a.y, __fmul_rn(xk, w.y));
    a.z = __fadd_rn(a.z, __fmul_rn(xk, w.z));
    a.w = __fadd_rn(a.w, __fmul_rn(xk, w.w));
  }
  a.x = __fadd_rn(a.x, bv.x);
  a.y = __fadd_rn(a.y, bv.y);
  a.z = __fadd_rn(a.z, bv.z);
  a.w = __fadd_rn(a.w, bv.w);
  *(float4*)(res + (size_t)b * O_N + o0) = a;
}

// ---------------------------------------------------------------------------
// Exact top-64 per row (R10 version, measured neutral vs R9).
// ---------------------------------------------------------------------------
__global__ __launch_bounds__(256) void topk_phase(
    const float* __restrict__ res, float* __restrict__ out) {
  __shared__ __align__(16) unsigned int hist[256];
  __shared__ unsigned int hist4[4 * 257];
  __shared__ unsigned int sel_u[64];
  __shared__ int sel_i[64];
  __shared__ int eqlist[128];
  __shared__ unsigned int s_cntgt, s_cnteq;
  __shared__ unsigned int s_remaining, s_prefix;

  const int t = threadIdx.x;
  const int b = blockIdx.x;
  const int w = t >> 6;

  hist[t] = 0u;
#pragma unroll
  for (int j = 0; j < 5; ++j) {
    const int z = t + 256 * j;
    if (z < 4 * 257) hist4[z] = 0u;
  }
  if (t == 0) {
    s_remaining = 64u;
    s_prefix = 0u;
    s_cntgt = 0u;
    s_cnteq = 0u;
  }

  unsigned int myu[16];
#pragma unroll
  for (int jf = 0; jf < 4; ++jf) {
    const float4 v =
        *(const float4*)(res + (size_t)b * O_N + 1024 * jf + 4 * t);
    const float fv[4] = {v.x, v.y, v.z, v.w};
#pragma unroll
    for (int c = 0; c < 4; ++c) {
      const unsigned int s = __float_as_uint(fv[c]);
      myu[jf * 4 + c] = (s & 0x80000000u) ? ~s : (s | 0x80000000u);
    }
  }
  __syncthreads();

  for (int round = 3; round >= 0; --round) {
    const int shift = round * 8;
    const unsigned int pfx = s_prefix;
    const unsigned int rem = s_remaining;
    if (round == 3) {
#pragma unroll
      for (int j = 0; j < 16; ++j)
        atomicAdd(&hist4[w * 257 + (myu[j] >> 24)], 1u);
    } else {
      const unsigned int himask = 0xFFFFFFFFu << (shift + 8);
#pragma unroll
      for (int j = 0; j < 16; ++j) {
        if ((myu[j] & himask) == (pfx & himask))
          atomicAdd(&hist[(myu[j] >> shift) & 255u], 1u);
      }
    }
    __syncthreads();
    if (t < 64) {
      uint4 h;
      if (round == 3) {
        h.x = hist4[0 * 257 + 4 * t + 0] + hist4[1 * 257 + 4 * t + 0] +
              hist4[2 * 257 + 4 * t + 0] + hist4[3 * 257 + 4 * t + 0];
        h.y = hist4[0 * 257 + 4 * t + 1] + hist4[1 * 257 + 4 * t + 1] +
              hist4[2 * 257 + 4 * t + 1] + hist4[3 * 257 + 4 * t + 1];
        h.z = hist4[0 * 257 + 4 * t + 2] + hist4[1 * 257 + 4 * t + 2] +
              hist4[2 * 257 + 4 * t + 2] + hist4[3 * 257 + 4 * t + 2];
        h.w = hist4[0 * 257 + 4 * t + 3] + hist4[1 * 257 + 4 * t + 3] +
              hist4[2 * 257 + 4 * t + 3] + hist4[3 * 257 + 4 * t + 3];
      } else {
        h = *(const uint4*)&hist[4 * t];
      }
      unsigned int s0 = h.x + h.y + h.z + h.w;
      unsigned int run = s0;
#pragma unroll
      for (int off = 1; off < 64; off <<= 1) {
        const unsigned int v = __shfl_down(run, off, 64);
        if (t + off < 64) run += v;
      }
      const unsigned int above = run - s0;
      unsigned int cge[4], cgt[4];
      cgt[3] = above;
      cge[3] = above + h.w;
      cgt[2] = cge[3];
      cge[2] = cge[3] + h.z;
      cgt[1] = cge[2];
      cge[1] = cge[2] + h.y;
      cgt[0] = cge[1];
      cge[0] = cge[1] + h.x;
#pragma unroll
      for (int j = 0; j < 4; ++j) {
        if (cge[j] >= rem && cgt[j] < rem) {
          s_prefix = pfx | ((unsigned int)(4 * t + j) << shift);
          s_remaining = rem - cgt[j];
        }
      }
      *(uint4*)&hist[4 * t] = make_uint4(0u, 0u, 0u, 0u);
    }
    __syncthreads();
  }
  const unsigned int ustar = s_prefix;

#pragma unroll
  for (int j = 0; j < 16; ++j) {
    const unsigned int u = myu[j];
    const int oi = 4 * t + (j & 3) + 1024 * (j >> 2);
    if (u > ustar) {
      unsigned int p = atomicAdd(&s_cntgt, 1u);
      sel_u[p] = u;
      sel_i[p] = oi;
    } else if (u == ustar) {
      unsigned int p = atomicAdd(&s_cnteq, 1u);
      if (p < 128u) eqlist[p] = oi;
    }
  }
  __syncthreads();

  if (t == 0 && s_cnteq > 1u) {
    int n = (int)(s_cnteq < 128u ? s_cnteq : 128u);
    for (int a = 1; a < n; ++a) {
      int v = eqlist[a];
      int c = a;
      while (c > 0 && eqlist[c - 1] > v) {
        eqlist[c] = eqlist[c - 1];
        --c;
      }
      eqlist[c] = v;
    }
  }
  __syncthreads();

  if (t < 64) {
    const int n_gt = (int)s_cntgt;
    unsigned int u;
    int oi;
    if (t < n_gt) {
      u = sel_u[t];
      oi = sel_i[t];
    } else {
      u = ustar;
      oi = eqlist[t - n_gt];
    }
    unsigned long long key =
        ((unsigned long long)(~u) << 32) | (unsigned int)oi;
    for (int kk = 2; kk <= 64; kk <<= 1) {
      for (int jj = kk >> 1; jj > 0; jj >>= 1) {
        unsigned long long partner = __shfl_xor(key, jj, 64);
        const bool up = ((t & kk) == 0);
        const bool lower = ((t & jj) == 0);
        unsigned long long mn = key < partner ? key : partner;
        unsigned long long mx = key < partner ? partner : key;
        key = (up == lower) ? mn : mx;
      }
    }
    const unsigned int su = ~(unsigned int)(key >> 32);
    const int so = (int)(key & 0xFFFFFFFFu);
    const float f = (su & 0x80000000u) ? __uint_as_float(su ^ 0x80000000u)
                                       : __uint_as_float(~su);
    out[b * 64 + t] = f;
    out[B_N * 64 + b * 64 + t] = (float)so;
  }
}

// ---------------------------------------------------------------------------
// Fallback: fused single-kernel path on raw W (used only if ws is too small).
// ---------------------------------------------------------------------------
__global__ __launch_bounds__(256) void selgemv_topk(
    const float* __restrict__ x, const float* __restrict__ Wsrc,
    const float* __restrict__ bias, const int* __restrict__ idx,
    float* __restrict__ out) {
  __shared__ float sx[K_N];
  __shared__ int si[K_N];
  __shared__ float svals[O_N];
  __shared__ unsigned int hist[256];
  __shared__ unsigned int scan[256];
  __shared__ unsigned int sel_u[64];
  __shared__ int sel_i[64];
  __shared__ int eqlist[128];
  __shared__ unsigned int s_T, s_ngt, s_cntgt, s_cnteq;
  __shared__ unsigned int s_remaining, s_prefix;

  const int t = threadIdx.x;
  const int b = blockIdx.x;

  if (t < K_N) {
    sx[t] = x[b * K_N + t];
    si[t] = idx[b * K_N + t];
  }
  if (t == 0) {
    s_remaining = 64u;
    s_prefix = 0u;
    s_cntgt = 0u;
    s_cnteq = 0u;
  }
  __syncthreads();

  float acc[16];
#pragma unroll
  for (int j = 0; j < 16; ++j) acc[j] = 0.0f;

  for (int k = 0; k < K_N; ++k) {
    const float xk = sx[k];
    const int ik = si[k];
#pragma unroll
    for (int j = 0; j < 4; ++j) {
      int o0 = (j * 256 + t) * 4;
#pragma unroll
      for (int c = 0; c < 4; ++c) {
        float w = Wsrc[(size_t)(o0 + c) * I_N + ik];
        acc[4 * j + c] = __fadd_rn(acc[4 * j + c], __fmul_rn(xk, w));
      }
    }
  }

#pragma unroll
  for (int j = 0; j < 4; ++j) {
    int g = j * 256 + t;
    float4 bb = ((const float4*)bias)[g];
    float4 r;
    r.x = __fadd_rn(acc[4 * j + 0], bb.x);
    r.y = __fadd_rn(acc[4 * j + 1], bb.y);
    r.z = __fadd_rn(acc[4 * j + 2], bb.z);
    r.w = __fadd_rn(acc[4 * j + 3], bb.w);
    ((float4*)svals)[g] = r;
  }
  __syncthreads();

  unsigned int myu[16];
#pragma unroll
  for (int j = 0; j < 16; ++j) {
    float f = svals[t + 256 * j];
    unsigned int s = __float_as_uint(f);
    myu[j] = (s & 0x80000000u) ? ~s : (s | 0x80000000u);
  }

  for (int round = 3; round >= 0; --round) {
    const int shift = round * 8;
    hist[t] = 0u;
    __syncthreads();
    const unsigned int pfx = s_prefix;
    const unsigned int rem = s_remaining;
    const unsigned int himask =
        (round == 3) ? 0u : (0xFFFFFFFFu << (shift + 8));
#pragma unroll
    for (int j = 0; j < 16; ++j) {
      if ((myu[j] & himask) == (pfx & himask))
        atomicAdd(&hist[(myu[j] >> shift) & 255u], 1u);
    }
    __syncthreads();
    scan[t] = hist[t];
    __syncthreads();
    for (int off = 1; off < 256; off <<= 1) {
      unsigned int v = (t + off < 256) ? scan[t + off] : 0u;
      __syncthreads();
      scan[t] += v;
      __syncthreads();
    }
    const unsigned int c_ge = scan[t];
    const unsigned int c_gt = (t < 255) ? scan[t + 1] : 0u;
    if (c_ge >= rem && c_gt < rem) {
      s_T = (unsigned int)t;
      s_ngt = c_gt;
    }
    __syncthreads();
    if (t == 0) {
      s_prefix |= (s_T << shift);
      s_remaining -= s_ngt;
    }
    __syncthreads();
  }
  const unsigned int ustar = s_prefix;

#pragma unroll
  for (int j = 0; j < 16; ++j) {
    const unsigned int u = myu[j];
    if (u > ustar) {
      unsigned int p = atomicAdd(&s_cntgt, 1u);
      sel_u[p] = u;
      sel_i[p] = t + 256 * j;
    } else if (u == ustar) {
      unsigned int p = atomicAdd(&s_cnteq, 1u);
      if (p < 128u) eqlist[p] = t + 256 * j;
    }
  }
  __syncthreads();

  if (t == 0 && s_cnteq > 1u) {
    int n = (int)(s_cnteq < 128u ? s_cnteq : 128u);
    for (int a = 1; a < n; ++a) {
      int v = eqlist[a];
      int c = a;
      while (c > 0 && eqlist[c - 1] > v) {
        eqlist[c] = eqlist[c - 1];
        --c;
      }
      eqlist[c] = v;
    }
  }
  __syncthreads();

  if (t < 64) {
    const int n_gt = (int)s_cntgt;
    unsigned int u;
    int oi;
    if (t < n_gt) {
      u = sel_u[t];
      oi = sel_i[t];
    } else {
      u = ustar;
      oi = eqlist[t - n_gt];
    }
    unsigned long long key =
        ((unsigned long long)(~u) << 32) | (unsigned int)oi;
    for (int kk = 2; kk <= 64; kk <<= 1) {
      for (int jj = kk >> 1; jj > 0; jj >>= 1) {
        unsigned long long partner = __shfl_xor(key, jj, 64);
        const bool up = ((t & kk) == 0);
        const bool lower = ((t & jj) == 0);
        unsigned long long mn = key < partner ? key : partner;
        unsigned long long mx = key < partner ? partner : key;
        key = (up == lower) ? mn : mx;
      }
    }
    const unsigned int su = ~(unsigned int)(key >> 32);
    const int so = (int)(key & 0xFFFFFFFFu);
    const float f = (su & 0x80000000u) ? __uint_as_float(su ^ 0x80000000u)
                                       : __uint_as_float(~su);
    out[b * 64 + t] = f;
    out[B_N * 64 + b * 64 + t] = (float)so;
  }
}

extern "C" void kernel_launch(void* const* d_in, const int* in_sizes, int n_in,
                              void* d_out, int out_size, void* d_ws,
                              size_t ws_size, hipStream_t stream) {
  const float* x = (const float*)d_in[0];     // (1024, 64)
  const float* W = (const float*)d_in[1];     // (4096, 4096)
  const float* bias = (const float*)d_in[2];  // (4096,)
  const int* idx = (const int*)d_in[3];       // (1024, 64) int32
  float* out = (float*)d_out;

  const size_t xT_bytes = (size_t)K_N * B_N * sizeof(float);   // 256 KB
  const size_t idxT_bytes = xT_bytes;                          // 256 KB
  const size_t res_bytes = (size_t)B_N * O_N * sizeof(float);  // 16 MB

  if (ws_size >= xT_bytes + idxT_bytes + res_bytes) {
    float* xT = (float*)d_ws;
    float* idxTf = (float*)((char*)d_ws + xT_bytes);
    float* res = (float*)((char*)d_ws + xT_bytes + idxT_bytes);
    xpose_small<<<32, 256, 0, stream>>>(x, (const float*)idx, xT, idxTf);
    gemv_lds<<<O_N / 4, 1024, 0, stream>>>(W, xT, (const int*)idxTf, bias,
                                           res);
    topk_phase<<<B_N, 256, 0, stream>>>(res, out);
  } else {
    selgemv_topk<<<B_N, 256, 0, stream>>>(x, W, bias, idx, out);
  }
}